// Round 2
// baseline (460.199 us; speedup 1.0000x reference)
//
#include <hip/hip_runtime.h>

#define SQ    2048
#define DIM   1024
#define NH    16
#define HDIM  64
#define BATCH 4

typedef unsigned short u16;
typedef __bf16 bf16x8 __attribute__((ext_vector_type(8)));
typedef float  f32x4  __attribute__((ext_vector_type(4)));
typedef u16    u16x8  __attribute__((ext_vector_type(8)));

__device__ __forceinline__ u16 f2bf(float f) {
  union { float f; unsigned u; } v; v.f = f;
  unsigned r = v.u + 0x7fffu + ((v.u >> 16) & 1u);
  return (u16)(r >> 16);
}

// ---------------------------------------------------------------------------
// x (fp32) -> bf16, vectorized float4 -> ushort4
// ---------------------------------------------------------------------------
__global__ __launch_bounds__(256)
void f32_to_bf16_vec(const float* __restrict__ in, u16* __restrict__ out, int n4)
{
  const int i = blockIdx.x * blockDim.x + threadIdx.x;
  if (i < n4) {
    const float4 v = ((const float4*)in)[i];
    ushort4 o;
    o.x = f2bf(v.x); o.y = f2bf(v.y); o.z = f2bf(v.z); o.w = f2bf(v.w);
    ((ushort4*)out)[i] = o;
  }
}

// ---------------------------------------------------------------------------
// Transpose fp32 [R][C] -> bf16 [C][R] via 32x32 LDS tile (+1 pad)
// ---------------------------------------------------------------------------
__global__ void transpose_f32_bf16(const float* __restrict__ in, u16* __restrict__ out,
                                   int R, int C)
{
  __shared__ u16 tile[32][33];
  const int bx = blockIdx.x * 32, by = blockIdx.y * 32;
  const int tx = threadIdx.x, ty = threadIdx.y;   // (32,8)
  #pragma unroll
  for (int i = 0; i < 32; i += 8)
    tile[ty + i][tx] = f2bf(in[(size_t)(by + ty + i) * C + bx + tx]);
  __syncthreads();
  #pragma unroll
  for (int i = 0; i < 32; i += 8)
    out[(size_t)(bx + ty + i) * R + by + tx] = tile[tx][ty + i];
}

// ---------------------------------------------------------------------------
// GEMM: C[M x N] = A[M x K](bf16) * Bt[N x K]^T(bf16) + bias[N](fp32)
// 128x128 tile/block, 4 waves (2x2), each wave 64x64 = 4x4 MFMA 16x16x32 tiles.
// QKV=1: scatter epilogue -> q[BH][S][HD], k[BH][S][HD], vT[BH][HD][S] (bf16)
// QKV=0: plain fp32 row-major store to of (final output)
// Verified layouts (learn_hip m89/m91): A[m=lane&15][k=quad*8+j],
// B[k=quad*8+j][n=lane&15] (from Bt rows), C/D col=lane&15 row=quad*4+reg.
// ---------------------------------------------------------------------------
#define LDT 40  // 32 + 8 pad, keeps 16B alignment (40*2=80 bytes/row)

template<int QKV>
__global__ __launch_bounds__(256)
void gemm_bt(const u16* __restrict__ A, const u16* __restrict__ Bt,
             const float* __restrict__ bias, int K,
             u16* __restrict__ o0, u16* __restrict__ o1, u16* __restrict__ o2,
             float* __restrict__ of)
{
  __shared__ __align__(16) u16 Als[128 * LDT];
  __shared__ __align__(16) u16 Bls[128 * LDT];

  const int t    = threadIdx.x;
  const int lane = t & 63, wave = t >> 6;
  const int l15  = lane & 15, quad = lane >> 4;
  const int wm   = (wave & 1) * 64, wn = (wave >> 1) * 64;
  const int m0   = blockIdx.y * 128, n0 = blockIdx.x * 128;

  const int srow = t >> 2;          // 0..63
  const int scol = (t & 3) * 8;     // 0,8,16,24

  f32x4 acc[4][4] = {};

  for (int k0 = 0; k0 < K; k0 += 32) {
    *(u16x8*)&Als[srow * LDT + scol]        = *(const u16x8*)&A [(size_t)(m0 + srow)      * K + k0 + scol];
    *(u16x8*)&Als[(srow + 64) * LDT + scol] = *(const u16x8*)&A [(size_t)(m0 + srow + 64) * K + k0 + scol];
    *(u16x8*)&Bls[srow * LDT + scol]        = *(const u16x8*)&Bt[(size_t)(n0 + srow)      * K + k0 + scol];
    *(u16x8*)&Bls[(srow + 64) * LDT + scol] = *(const u16x8*)&Bt[(size_t)(n0 + srow + 64) * K + k0 + scol];
    __syncthreads();

    bf16x8 af[4], bfr[4];
    #pragma unroll
    for (int i = 0; i < 4; ++i) af[i]  = *(const bf16x8*)&Als[(wm + 16*i + l15) * LDT + quad * 8];
    #pragma unroll
    for (int j = 0; j < 4; ++j) bfr[j] = *(const bf16x8*)&Bls[(wn + 16*j + l15) * LDT + quad * 8];
    #pragma unroll
    for (int i = 0; i < 4; ++i)
      #pragma unroll
      for (int j = 0; j < 4; ++j)
        acc[i][j] = __builtin_amdgcn_mfma_f32_16x16x32_bf16(af[i], bfr[j], acc[i][j], 0, 0, 0);
    __syncthreads();
  }

  #pragma unroll
  for (int j = 0; j < 4; ++j) {
    const int n = n0 + wn + 16*j + l15;
    const float bn = bias[n];
    #pragma unroll
    for (int i = 0; i < 4; ++i) {
      #pragma unroll
      for (int r = 0; r < 4; ++r) {
        const int m = m0 + wm + 16*i + quad * 4 + r;
        const float val = acc[i][j][r] + bn;
        if (QKV) {
          const int sec = n >> 10, d = n & 1023;
          const int h = d >> 6, hd = d & 63;
          const int b = m >> 11, s = m & 2047;
          const int bh = b * NH + h;
          if (sec == 0)      o0[((size_t)bh * SQ + s) * HDIM + hd] = f2bf(val);
          else if (sec == 1) o1[((size_t)bh * SQ + s) * HDIM + hd] = f2bf(val);
          else               o2[((size_t)bh * HDIM + hd) * SQ + s] = f2bf(val);
        } else {
          of[(size_t)m * DIM + n] = val;
        }
      }
    }
  }
}

// ---------------------------------------------------------------------------
// Causal flash attention (all bf16 ws). grid = (SQ/64, BATCH*NH), 256 threads.
// Each wave owns 16 Q rows; KV tiles of 64 staged in LDS (K as [kv][hd],
// V pre-transposed [hd][kv] so PV's B-operand reads are contiguous).
// P converts C-layout -> A-layout via per-wave LDS round-trip (m120 pattern;
// intra-wave DS ops are in-order, no barrier needed).
// ---------------------------------------------------------------------------
#define LKV 72  // 64 + 8 pad (144 bytes/row, 16B aligned)

__global__ __launch_bounds__(256)
void attn_fused(const u16* __restrict__ q_ws, const u16* __restrict__ k_ws,
                const u16* __restrict__ v_t, u16* __restrict__ y_ws)
{
  __shared__ __align__(16) u16 Kls[64 * LKV];
  __shared__ __align__(16) u16 Vls[64 * LKV];
  __shared__ __align__(16) u16 Pls[4][16 * LKV];

  const int qt = blockIdx.x;
  const int bh = blockIdx.y;
  const int b = bh >> 4, h = bh & 15;
  const int t = threadIdx.x;
  const int lane = t & 63, wave = t >> 6;
  const int l15 = lane & 15, quad = lane >> 4;

  const u16* Q  = q_ws + (size_t)bh * SQ * HDIM;
  const u16* Kp = k_ws + (size_t)bh * SQ * HDIM;
  const u16* Vp = v_t + (size_t)bh * HDIM * SQ;

  const int qrow = qt * 64 + wave * 16;

  bf16x8 qf[2];
  #pragma unroll
  for (int ks = 0; ks < 2; ++ks)
    qf[ks] = *(const bf16x8*)&Q[(size_t)(qrow + l15) * HDIM + ks * 32 + quad * 8];

  f32x4 o[4] = {};
  float m_r[4] = {-1e30f, -1e30f, -1e30f, -1e30f};
  float l_r[4] = {};

  const int srow = t >> 2, scol = (t & 3) * 8;

  for (int kvt = 0; kvt <= qt; ++kvt) {
    const int kv0 = kvt * 64;
    *(u16x8*)&Kls[srow * LKV + scol]      = *(const u16x8*)&Kp[(size_t)(kv0 + srow) * HDIM + scol];
    *(u16x8*)&Kls[srow * LKV + scol + 32] = *(const u16x8*)&Kp[(size_t)(kv0 + srow) * HDIM + scol + 32];
    *(u16x8*)&Vls[srow * LKV + scol]      = *(const u16x8*)&Vp[(size_t)srow * SQ + kv0 + scol];
    *(u16x8*)&Vls[srow * LKV + scol + 32] = *(const u16x8*)&Vp[(size_t)srow * SQ + kv0 + scol + 32];
    __syncthreads();

    // S = Q K^T (16 x 64), 4 n-tiles x 2 k-steps
    f32x4 sacc[4] = {};
    #pragma unroll
    for (int ks = 0; ks < 2; ++ks) {
      #pragma unroll
      for (int jn = 0; jn < 4; ++jn) {
        bf16x8 kf = *(const bf16x8*)&Kls[(16*jn + l15) * LKV + ks * 32 + quad * 8];
        sacc[jn] = __builtin_amdgcn_mfma_f32_16x16x32_bf16(qf[ks], kf, sacc[jn], 0, 0, 0);
      }
    }

    const bool diag = (kvt == qt);
    float p[4][4];
    #pragma unroll
    for (int r = 0; r < 4; ++r) {
      const int qg = qrow + quad * 4 + r;
      float tmax = -1e30f;
      #pragma unroll
      for (int jn = 0; jn < 4; ++jn) {
        float sv = sacc[jn][r] * 0.125f;           // 1/sqrt(64)
        if (diag && (kv0 + 16*jn + l15) > qg) sv = -1e30f;
        p[jn][r] = sv;
        tmax = fmaxf(tmax, sv);
      }
      #pragma unroll
      for (int off = 1; off < 16; off <<= 1)
        tmax = fmaxf(tmax, __shfl_xor(tmax, off));
      const float mnew  = fmaxf(m_r[r], tmax);
      const float alpha = __expf(m_r[r] - mnew);
      float rsum = 0.f;
      #pragma unroll
      for (int jn = 0; jn < 4; ++jn) {
        const float pv = __expf(p[jn][r] - mnew);
        p[jn][r] = pv;
        rsum += pv;
      }
      #pragma unroll
      for (int off = 1; off < 16; off <<= 1)
        rsum += __shfl_xor(rsum, off);
      l_r[r] = l_r[r] * alpha + rsum;
      m_r[r] = mnew;
      #pragma unroll
      for (int jn = 0; jn < 4; ++jn) o[jn][r] *= alpha;
    }

    // C-layout -> A-layout round trip through per-wave LDS (wave-local)
    #pragma unroll
    for (int r = 0; r < 4; ++r)
      #pragma unroll
      for (int jn = 0; jn < 4; ++jn)
        Pls[wave][(quad * 4 + r) * LKV + 16*jn + l15] = f2bf(p[jn][r]);

    bf16x8 pf[2];
    #pragma unroll
    for (int ks = 0; ks < 2; ++ks)
      pf[ks] = *(const bf16x8*)&Pls[wave][l15 * LKV + ks * 32 + quad * 8];

    #pragma unroll
    for (int ks = 0; ks < 2; ++ks)
      #pragma unroll
      for (int jn = 0; jn < 4; ++jn) {
        bf16x8 vf = *(const bf16x8*)&Vls[(16*jn + l15) * LKV + ks * 32 + quad * 8];
        o[jn] = __builtin_amdgcn_mfma_f32_16x16x32_bf16(pf[ks], vf, o[jn], 0, 0, 0);
      }

    __syncthreads();
  }

  #pragma unroll
  for (int r = 0; r < 4; ++r) {
    const int qg = qrow + quad * 4 + r;
    const float inv_l = 1.0f / l_r[r];
    #pragma unroll
    for (int jn = 0; jn < 4; ++jn) {
      const int hd = 16*jn + l15;
      y_ws[((size_t)b * SQ + qg) * DIM + h * HDIM + hd] = f2bf(o[jn][r] * inv_l);
    }
  }
}

// ---------------------------------------------------------------------------
extern "C" void kernel_launch(void* const* d_in, const int* in_sizes, int n_in,
                              void* d_out, int out_size, void* d_ws, size_t ws_size,
                              hipStream_t stream)
{
  const float* x      = (const float*)d_in[0];   // [4,2048,1024] fp32
  const float* W_attn = (const float*)d_in[1];   // [1024,3072]
  const float* b_attn = (const float*)d_in[2];   // [3072]
  const float* W_proj = (const float*)d_in[3];   // [1024,1024]
  const float* b_proj = (const float*)d_in[4];   // [1024]
  float* out = (float*)d_out;                    // [4,2048,1024] fp32

  char* ws = (char*)d_ws;
  u16* WattnT = (u16*)(ws);                  // [3072][1024] bf16, 6.29 MB
  u16* WprojT = (u16*)(ws + 6291456);        // [1024][1024] bf16, 2.10 MB
  u16* xb     = (u16*)(ws + 8388608);        // [8192][1024] bf16, 16.8 MB
  u16* y_ws   = xb;                          // aliases xb (dead after QKV GEMM)
  u16* q_ws   = (u16*)(ws + 25165824);       // [64][2048][64] bf16
  u16* k_ws   = (u16*)(ws + 41943040);       // [64][2048][64] bf16
  u16* v_tw   = (u16*)(ws + 58720256);       // [64][64][2048] bf16 (transposed V)
  // total: 75.5 MB

  const dim3 tb(32, 8);
  transpose_f32_bf16<<<dim3(3 * DIM / 32, DIM / 32), tb, 0, stream>>>(W_attn, WattnT, DIM, 3 * DIM);
  transpose_f32_bf16<<<dim3(DIM / 32, DIM / 32), tb, 0, stream>>>(W_proj, WprojT, DIM, DIM);
  f32_to_bf16_vec<<<(BATCH * SQ * DIM / 4 + 255) / 256, 256, 0, stream>>>(x, xb, BATCH * SQ * DIM / 4);

  gemm_bt<1><<<dim3(3 * DIM / 128, BATCH * SQ / 128), 256, 0, stream>>>(
      xb, WattnT, b_attn, DIM, q_ws, k_ws, v_tw, nullptr);

  attn_fused<<<dim3(SQ / 64, BATCH * NH), 256, 0, stream>>>(q_ws, k_ws, v_tw, y_ws);

  gemm_bt<0><<<dim3(DIM / 128, BATCH * SQ / 128), 256, 0, stream>>>(
      y_ws, WprojT, b_proj, DIM, nullptr, nullptr, nullptr, out);
}

// Round 3
// 311.887 us; speedup vs baseline: 1.4755x; 1.4755x over previous
//
#include <hip/hip_runtime.h>

#define SQ    2048
#define DIM   1024
#define NH    16
#define HDIM  64
#define BATCH 4

typedef unsigned short u16;
typedef __bf16 bf16x8 __attribute__((ext_vector_type(8)));
typedef float  f32x4  __attribute__((ext_vector_type(4)));
typedef u16    u16x8  __attribute__((ext_vector_type(8)));

__device__ __forceinline__ u16 f2bf(float f) {
  union { float f; unsigned u; } v; v.f = f;
  unsigned r = v.u + 0x7fffu + ((v.u >> 16) & 1u);
  return (u16)(r >> 16);
}

// async global->LDS, 16B per lane. LDS dest is wave-uniform base + lane*16.
__device__ __forceinline__ void gll16(const u16* g, u16* l) {
  __builtin_amdgcn_global_load_lds((const __attribute__((address_space(1))) void*)g,
                                   (__attribute__((address_space(3))) void*)l,
                                   16, 0, 0);
}

// ---------------------------------------------------------------------------
// x (fp32) -> bf16, vectorized float4 -> ushort4
// ---------------------------------------------------------------------------
__global__ __launch_bounds__(256)
void f32_to_bf16_vec(const float* __restrict__ in, u16* __restrict__ out, int n4)
{
  const int i = blockIdx.x * blockDim.x + threadIdx.x;
  if (i < n4) {
    const float4 v = ((const float4*)in)[i];
    ushort4 o;
    o.x = f2bf(v.x); o.y = f2bf(v.y); o.z = f2bf(v.z); o.w = f2bf(v.w);
    ((ushort4*)out)[i] = o;
  }
}

// ---------------------------------------------------------------------------
// Transpose fp32 [R][C] -> bf16 [C][R] via 32x32 LDS tile (+1 pad)
// ---------------------------------------------------------------------------
__global__ void transpose_f32_bf16(const float* __restrict__ in, u16* __restrict__ out,
                                   int R, int C)
{
  __shared__ u16 tile[32][33];
  const int bx = blockIdx.x * 32, by = blockIdx.y * 32;
  const int tx = threadIdx.x, ty = threadIdx.y;   // (32,8)
  #pragma unroll
  for (int i = 0; i < 32; i += 8)
    tile[ty + i][tx] = f2bf(in[(size_t)(by + ty + i) * C + bx + tx]);
  __syncthreads();
  #pragma unroll
  for (int i = 0; i < 32; i += 8)
    out[(size_t)(bx + ty + i) * R + by + tx] = tile[tx][ty + i];
}

// ---------------------------------------------------------------------------
// GEMM (m97 structure): C[M x N] = A[M x K](bf16) * Bt[N x K]^T(bf16) + bias
// 128x128 tile, 4 waves, 16x16x32 MFMA. Staging via global_load_lds width=16
// into UNPADDED [128][32] LDS (64B rows; b128 fragment reads are 8/bank min).
// QKV=1: scatter epilogue -> q[BH][S][HD], k[BH][S][HD], vT[BH][HD][S] (bf16)
// QKV=0: fp32 row-major store (final output)
// ---------------------------------------------------------------------------
#define LDT 32

template<int QKV>
__global__ __launch_bounds__(256)
void gemm_bt(const u16* __restrict__ A, const u16* __restrict__ Bt,
             const float* __restrict__ bias, int K,
             u16* __restrict__ o0, u16* __restrict__ o1, u16* __restrict__ o2,
             float* __restrict__ of)
{
  __shared__ __align__(16) u16 Als[128 * LDT];
  __shared__ __align__(16) u16 Bls[128 * LDT];

  const int t    = threadIdx.x;
  const int lane = t & 63, wave = t >> 6;
  const int l15  = lane & 15, quad = lane >> 4;
  const int wm   = (wave & 1) * 64, wn = (wave >> 1) * 64;
  const int m0   = blockIdx.y * 128, n0 = blockIdx.x * 128;

  // staging geometry: each wave covers rows [wave*32, wave*32+32) in 2 insts
  const int srow = wave * 32 + (lane >> 2);   // rows via lane>>2 (16 rows/inst)
  const int scol = (lane & 3) * 8;            // 16B chunk within 64B row

  f32x4 acc[4][4] = {};

  for (int k0 = 0; k0 < K; k0 += 32) {
    const u16* ga = A  + (size_t)(m0 + srow) * K + k0 + scol;
    const u16* gb = Bt + (size_t)(n0 + srow) * K + k0 + scol;
    gll16(ga,             &Als[(wave * 32)      * LDT]);
    gll16(ga + 16 * K,    &Als[(wave * 32 + 16) * LDT]);
    gll16(gb,             &Bls[(wave * 32)      * LDT]);
    gll16(gb + 16 * K,    &Bls[(wave * 32 + 16) * LDT]);
    __syncthreads();

    bf16x8 af[4], bfr[4];
    #pragma unroll
    for (int i = 0; i < 4; ++i) af[i]  = *(const bf16x8*)&Als[(wm + 16*i + l15) * LDT + quad * 8];
    #pragma unroll
    for (int j = 0; j < 4; ++j) bfr[j] = *(const bf16x8*)&Bls[(wn + 16*j + l15) * LDT + quad * 8];
    #pragma unroll
    for (int i = 0; i < 4; ++i)
      #pragma unroll
      for (int j = 0; j < 4; ++j)
        acc[i][j] = __builtin_amdgcn_mfma_f32_16x16x32_bf16(af[i], bfr[j], acc[i][j], 0, 0, 0);
    __syncthreads();
  }

  #pragma unroll
  for (int j = 0; j < 4; ++j) {
    const int n = n0 + wn + 16*j + l15;
    const float bn = bias[n];
    #pragma unroll
    for (int i = 0; i < 4; ++i) {
      #pragma unroll
      for (int r = 0; r < 4; ++r) {
        const int m = m0 + wm + 16*i + quad * 4 + r;
        const float val = acc[i][j][r] + bn;
        if (QKV) {
          const int sec = n >> 10, d = n & 1023;
          const int h = d >> 6, hd = d & 63;
          const int b = m >> 11, s = m & 2047;
          const int bh = b * NH + h;
          if (sec == 0)      o0[((size_t)bh * SQ + s) * HDIM + hd] = f2bf(val);
          else if (sec == 1) o1[((size_t)bh * SQ + s) * HDIM + hd] = f2bf(val);
          else               o2[((size_t)bh * HDIM + hd) * SQ + s] = f2bf(val);
        } else {
          of[(size_t)m * DIM + n] = val;
        }
      }
    }
  }
}

// ---------------------------------------------------------------------------
// Causal flash attention, S^T formulation.
// grid = (BATCH*NH, SQ/128); block = 256 (4 waves x 32 Q rows).
// Per KV tile of 64: stage K/V via global_load_lds into 4 unpadded [64][32]
// half-tiles; S^T = K*Q^T (softmax reduction mostly in-register, 2 shuffles);
// P^T -> A-layout via wave-local LDS (packed b64 writes); O = P*V.
// bh on blockIdx.x => XCD (= blkid%8) sees 8 heads' KV = 4MB = L2 size.
// qb reversed so heavy blocks dispatch first.
// ---------------------------------------------------------------------------
#define LP 72  // 64 + 8 pad (144B rows; b64 writes land 4/bank = conflict-free)

__global__ __launch_bounds__(256)
void attn_fused(const u16* __restrict__ q_ws, const u16* __restrict__ k_ws,
                const u16* __restrict__ v_t, u16* __restrict__ y_ws)
{
  __shared__ __align__(16) u16 K0[64 * 32], K1[64 * 32];
  __shared__ __align__(16) u16 V0[64 * 32], V1[64 * 32];
  __shared__ __align__(16) u16 Pls[4][32 * LP];

  const int bh = blockIdx.x;
  const int qb = (gridDim.y - 1) - blockIdx.y;   // heavy-first
  const int b = bh >> 4, h = bh & 15;
  const int t = threadIdx.x;
  const int lane = t & 63, wave = t >> 6;
  const int l15 = lane & 15, quad = lane >> 4;

  const u16* Q  = q_ws + (size_t)bh * SQ * HDIM;
  const u16* Kp = k_ws + (size_t)bh * SQ * HDIM;
  const u16* Vp = v_t  + (size_t)bh * HDIM * SQ;

  const int qrow = qb * 128 + wave * 32;   // this wave's 32 rows

  // Q fragments (reused every tile): qf[qi][ks] = Q[qrow+16qi+l15][32ks+8quad..+8]
  bf16x8 qf[2][2];
  #pragma unroll
  for (int qi = 0; qi < 2; ++qi)
    #pragma unroll
    for (int ks = 0; ks < 2; ++ks)
      qf[qi][ks] = *(const bf16x8*)&Q[(size_t)(qrow + 16*qi + l15) * HDIM + ks * 32 + quad * 8];

  f32x4 o[2][4] = {};                 // O rows=16mi+quad*4+r, cols=16n+l15
  float m_q[2] = {-1e30f, -1e30f};    // per-lane state for q = qrow+16qi+l15
  float l_q[2] = {};

  // staging geometry: wave covers 16 rows of each half-tile per inst
  const int sr = wave * 16 + (lane >> 2);
  const int sc = (lane & 3) * 8;
  u16* const ldst_k0 = &K0[wave * 512];  // wave*1024B, +lane*16B by HW
  u16* const ldst_k1 = &K1[wave * 512];
  u16* const ldst_v0 = &V0[wave * 512];
  u16* const ldst_v1 = &V1[wave * 512];

  const int ntiles = 2 * qb + 2;
  for (int kvt = 0; kvt < ntiles; ++kvt) {
    const int kv0 = kvt * 64;
    gll16(&Kp[(size_t)(kv0 + sr) * HDIM + sc],      ldst_k0);
    gll16(&Kp[(size_t)(kv0 + sr) * HDIM + sc + 32], ldst_k1);
    gll16(&Vp[(size_t)sr * SQ + kv0 + sc],          ldst_v0);
    gll16(&Vp[(size_t)sr * SQ + kv0 + sc + 32],     ldst_v1);
    __syncthreads();

    if (kv0 <= qrow + 31) {          // wave-uniform: tile intersects causal range
      // S^T = K * Q^T : st[kt][qi], rows kv=kv0+16kt+quad*4+r, cols q=qrow+16qi+l15
      f32x4 st[4][2] = {};
      #pragma unroll
      for (int ks = 0; ks < 2; ++ks) {
        const u16* Kls = ks ? K1 : K0;
        #pragma unroll
        for (int kt = 0; kt < 4; ++kt) {
          bf16x8 kf = *(const bf16x8*)&Kls[(16*kt + l15) * 32 + quad * 8];
          #pragma unroll
          for (int qi = 0; qi < 2; ++qi)
            st[kt][qi] = __builtin_amdgcn_mfma_f32_16x16x32_bf16(kf, qf[qi][ks], st[kt][qi], 0, 0, 0);
        }
      }

      const bool needs_mask = (kv0 + 63) > qrow;
      float alpha[2];
      #pragma unroll
      for (int qi = 0; qi < 2; ++qi) {
        const int q = qrow + 16*qi + l15;
        float tmax = -1e30f;
        #pragma unroll
        for (int kt = 0; kt < 4; ++kt)
          #pragma unroll
          for (int r = 0; r < 4; ++r) {
            float sv = st[kt][qi][r] * 0.125f;   // 1/sqrt(64)
            if (needs_mask && (kv0 + 16*kt + quad*4 + r) > q) sv = -1e30f;
            st[kt][qi][r] = sv;
            tmax = fmaxf(tmax, sv);
          }
        tmax = fmaxf(tmax, __shfl_xor(tmax, 16));
        tmax = fmaxf(tmax, __shfl_xor(tmax, 32));
        const float mnew = fmaxf(m_q[qi], tmax);
        alpha[qi] = __expf(m_q[qi] - mnew);
        float rsum = 0.f;
        #pragma unroll
        for (int kt = 0; kt < 4; ++kt)
          #pragma unroll
          for (int r = 0; r < 4; ++r) {
            const float pv = __expf(st[kt][qi][r] - mnew);
            st[kt][qi][r] = pv;
            rsum += pv;
          }
        rsum += __shfl_xor(rsum, 16);
        rsum += __shfl_xor(rsum, 32);
        l_q[qi] = l_q[qi] * alpha[qi] + rsum;
        m_q[qi] = mnew;
      }

      // P^T (C-layout) -> P[q][kv] in LDS, packed 4 bf16 per b64 write
      #pragma unroll
      for (int qi = 0; qi < 2; ++qi)
        #pragma unroll
        for (int kt = 0; kt < 4; ++kt) {
          ushort4 pk;
          pk.x = f2bf(st[kt][qi][0]); pk.y = f2bf(st[kt][qi][1]);
          pk.z = f2bf(st[kt][qi][2]); pk.w = f2bf(st[kt][qi][3]);
          *(ushort4*)&Pls[wave][(16*qi + l15) * LP + 16*kt + quad * 4] = pk;
        }

      // rescale O by alpha (row-indexed: broadcast from q-state lanes)
      #pragma unroll
      for (int mi = 0; mi < 2; ++mi)
        #pragma unroll
        for (int r = 0; r < 4; ++r) {
          const float ar = __shfl(alpha[mi], quad * 4 + r);
          #pragma unroll
          for (int n = 0; n < 4; ++n) o[mi][n][r] *= ar;
        }

      // O += P * V  (A = P from LDS, B = V^T half-tiles)
      #pragma unroll
      for (int ks = 0; ks < 2; ++ks) {
        const u16* Vls = ks ? V1 : V0;
        bf16x8 vf[4];
        #pragma unroll
        for (int n = 0; n < 4; ++n)
          vf[n] = *(const bf16x8*)&Vls[(16*n + l15) * 32 + quad * 8];
        #pragma unroll
        for (int mi = 0; mi < 2; ++mi) {
          bf16x8 pa = *(const bf16x8*)&Pls[wave][(16*mi + l15) * LP + ks * 32 + quad * 8];
          #pragma unroll
          for (int n = 0; n < 4; ++n)
            o[mi][n] = __builtin_amdgcn_mfma_f32_16x16x32_bf16(pa, vf[n], o[mi][n], 0, 0, 0);
        }
      }
    }
    __syncthreads();
  }

  // epilogue: normalize by l (row-indexed broadcast) and store
  #pragma unroll
  for (int mi = 0; mi < 2; ++mi)
    #pragma unroll
    for (int r = 0; r < 4; ++r) {
      const float lr = __shfl(l_q[mi], quad * 4 + r);
      const float inv = 1.0f / lr;
      const int qg = qrow + 16*mi + quad * 4 + r;
      #pragma unroll
      for (int n = 0; n < 4; ++n)
        y_ws[((size_t)b * SQ + qg) * DIM + h * HDIM + 16*n + l15] = f2bf(o[mi][n][r] * inv);
    }
}

// ---------------------------------------------------------------------------
extern "C" void kernel_launch(void* const* d_in, const int* in_sizes, int n_in,
                              void* d_out, int out_size, void* d_ws, size_t ws_size,
                              hipStream_t stream)
{
  const float* x      = (const float*)d_in[0];   // [4,2048,1024] fp32
  const float* W_attn = (const float*)d_in[1];   // [1024,3072]
  const float* b_attn = (const float*)d_in[2];   // [3072]
  const float* W_proj = (const float*)d_in[3];   // [1024,1024]
  const float* b_proj = (const float*)d_in[4];   // [1024]
  float* out = (float*)d_out;                    // [4,2048,1024] fp32

  char* ws = (char*)d_ws;
  u16* WattnT = (u16*)(ws);                  // [3072][1024] bf16, 6.29 MB
  u16* WprojT = (u16*)(ws + 6291456);        // [1024][1024] bf16, 2.10 MB
  u16* xb     = (u16*)(ws + 8388608);        // [8192][1024] bf16, 16.8 MB
  u16* y_ws   = xb;                          // aliases xb (dead after QKV GEMM)
  u16* q_ws   = (u16*)(ws + 25165824);       // [64][2048][64] bf16
  u16* k_ws   = (u16*)(ws + 41943040);       // [64][2048][64] bf16
  u16* v_tw   = (u16*)(ws + 58720256);       // [64][64][2048] bf16 (transposed V)
  // total: 75.5 MB

  const dim3 tb(32, 8);
  transpose_f32_bf16<<<dim3(3 * DIM / 32, DIM / 32), tb, 0, stream>>>(W_attn, WattnT, DIM, 3 * DIM);
  transpose_f32_bf16<<<dim3(DIM / 32, DIM / 32), tb, 0, stream>>>(W_proj, WprojT, DIM, DIM);
  f32_to_bf16_vec<<<(BATCH * SQ * DIM / 4 + 255) / 256, 256, 0, stream>>>(x, xb, BATCH * SQ * DIM / 4);

  gemm_bt<1><<<dim3(3 * DIM / 128, BATCH * SQ / 128), 256, 0, stream>>>(
      xb, WattnT, b_attn, DIM, q_ws, k_ws, v_tw, nullptr);

  attn_fused<<<dim3(BATCH * NH, SQ / 128), 256, 0, stream>>>(q_ws, k_ws, v_tw, y_ws);

  gemm_bt<0><<<dim3(DIM / 128, BATCH * SQ / 128), 256, 0, stream>>>(
      y_ws, WprojT, b_proj, DIM, nullptr, nullptr, nullptr, out);
}

// Round 4
// 297.075 us; speedup vs baseline: 1.5491x; 1.0499x over previous
//
#include <hip/hip_runtime.h>

#define SQ    2048
#define DIM   1024
#define NH    16
#define HDIM  64
#define BATCH 4

typedef unsigned short u16;
typedef __bf16 bf16x8 __attribute__((ext_vector_type(8)));
typedef float  f32x4  __attribute__((ext_vector_type(4)));
typedef u16    u16x8  __attribute__((ext_vector_type(8)));

__device__ __forceinline__ u16 f2bf(float f) {
  union { float f; unsigned u; } v; v.f = f;
  unsigned r = v.u + 0x7fffu + ((v.u >> 16) & 1u);
  return (u16)(r >> 16);
}

// async global->LDS, 16B per lane. LDS dest is wave-uniform base + lane*16.
__device__ __forceinline__ void gll16(const u16* g, u16* l) {
  __builtin_amdgcn_global_load_lds((const __attribute__((address_space(1))) void*)g,
                                   (__attribute__((address_space(3))) void*)l,
                                   16, 0, 0);
}

// ---------------------------------------------------------------------------
// x (fp32) -> bf16, vectorized float4 -> ushort4
// ---------------------------------------------------------------------------
__global__ __launch_bounds__(256)
void f32_to_bf16_vec(const float* __restrict__ in, u16* __restrict__ out, int n4)
{
  const int i = blockIdx.x * blockDim.x + threadIdx.x;
  if (i < n4) {
    const float4 v = ((const float4*)in)[i];
    ushort4 o;
    o.x = f2bf(v.x); o.y = f2bf(v.y); o.z = f2bf(v.z); o.w = f2bf(v.w);
    ((ushort4*)out)[i] = o;
  }
}

// ---------------------------------------------------------------------------
// Transpose fp32 [R][C] -> bf16 [C][R] via 32x32 LDS tile (+1 pad)
// ---------------------------------------------------------------------------
__global__ void transpose_f32_bf16(const float* __restrict__ in, u16* __restrict__ out,
                                   int R, int C)
{
  __shared__ u16 tile[32][33];
  const int bx = blockIdx.x * 32, by = blockIdx.y * 32;
  const int tx = threadIdx.x, ty = threadIdx.y;   // (32,8)
  #pragma unroll
  for (int i = 0; i < 32; i += 8)
    tile[ty + i][tx] = f2bf(in[(size_t)(by + ty + i) * C + bx + tx]);
  __syncthreads();
  #pragma unroll
  for (int i = 0; i < 32; i += 8)
    out[(size_t)(bx + ty + i) * R + by + tx] = tile[tx][ty + i];
}

// ---------------------------------------------------------------------------
// GEMM: C[M x N] = A[M x K](bf16) * Bt[N x K]^T(bf16) + bias[N](fp32)
// 128x128 tile, 4 waves, 16x16x32 MFMA, BK=64 via 4 half-buffers with 64B
// rows (keeps the verified conflict-minimal ds_read_b128 pattern), staged by
// global_load_lds width=16.
// MODE 0: fp32 row-major store (final output)
// MODE 1: QK scatter -> q[BH][S][HD], k[BH][S][HD] (bf16, 32B segments)
// MODE 2: V with SWAPPED MFMA operands -> C^T in C-layout -> coalesced
//         vT[BH][HD][S] stores (col=lane&15 indexes s). Bt/bias pre-offset
//         by caller to the V section.
// ---------------------------------------------------------------------------
template<int MODE>
__global__ __launch_bounds__(256)
void gemm_bt(const u16* __restrict__ A, const u16* __restrict__ Bt,
             const float* __restrict__ bias, int K,
             u16* __restrict__ o0, u16* __restrict__ o1, float* __restrict__ of)
{
  __shared__ __align__(16) u16 A0[128 * 32], A1[128 * 32];
  __shared__ __align__(16) u16 B0[128 * 32], B1[128 * 32];

  const int t    = threadIdx.x;
  const int lane = t & 63, wave = t >> 6;
  const int l15  = lane & 15, quad = lane >> 4;
  const int wm   = (wave & 1) * 64, wn = (wave >> 1) * 64;
  const int m0   = blockIdx.y * 128, n0 = blockIdx.x * 128;

  // staging: each gll16 covers 16 rows x 64B; per wave 32 rows x two k-halves
  const int srow = wave * 32 + (lane >> 2);
  const int scol = (lane & 3) * 8;

  f32x4 acc[4][4] = {};

  for (int k0 = 0; k0 < K; k0 += 64) {
    const u16* ga = A  + (size_t)(m0 + srow) * K + k0 + scol;
    const u16* gb = Bt + (size_t)(n0 + srow) * K + k0 + scol;
    gll16(ga,              &A0[(wave * 32)      * 32]);
    gll16(ga + 32,         &A1[(wave * 32)      * 32]);
    gll16(ga + 16 * K,     &A0[(wave * 32 + 16) * 32]);
    gll16(ga + 16 * K + 32,&A1[(wave * 32 + 16) * 32]);
    gll16(gb,              &B0[(wave * 32)      * 32]);
    gll16(gb + 32,         &B1[(wave * 32)      * 32]);
    gll16(gb + 16 * K,     &B0[(wave * 32 + 16) * 32]);
    gll16(gb + 16 * K + 32,&B1[(wave * 32 + 16) * 32]);
    __syncthreads();

    #pragma unroll
    for (int ks = 0; ks < 2; ++ks) {
      const u16* Als = ks ? A1 : A0;
      const u16* Bls = ks ? B1 : B0;
      bf16x8 af[4], bfr[4];
      #pragma unroll
      for (int i = 0; i < 4; ++i) af[i]  = *(const bf16x8*)&Als[(wm + 16*i + l15) * 32 + quad * 8];
      #pragma unroll
      for (int j = 0; j < 4; ++j) bfr[j] = *(const bf16x8*)&Bls[(wn + 16*j + l15) * 32 + quad * 8];
      #pragma unroll
      for (int i = 0; i < 4; ++i)
        #pragma unroll
        for (int j = 0; j < 4; ++j)
          acc[i][j] = (MODE == 2)
            ? __builtin_amdgcn_mfma_f32_16x16x32_bf16(bfr[j], af[i], acc[i][j], 0, 0, 0)
            : __builtin_amdgcn_mfma_f32_16x16x32_bf16(af[i], bfr[j], acc[i][j], 0, 0, 0);
    }
    __syncthreads();
  }

  if (MODE == 2) {
    // value(i,j,r) = C[m = m0+wm+16i+l15][n = n0+wn+16j+quad*4+r]
    #pragma unroll
    for (int j = 0; j < 4; ++j) {
      #pragma unroll
      for (int r = 0; r < 4; ++r) {
        const int d = n0 + wn + 16*j + quad * 4 + r;   // 0..1023 within V
        const float bn = bias[d];
        const int h = d >> 6, hd = d & 63;
        #pragma unroll
        for (int i = 0; i < 4; ++i) {
          const int m = m0 + wm + 16*i + l15;
          const int b = m >> 11, s = m & 2047;
          o0[(((size_t)(b * NH + h)) * HDIM + hd) * SQ + s] = f2bf(acc[i][j][r] + bn);
        }
      }
    }
  } else {
    #pragma unroll
    for (int j = 0; j < 4; ++j) {
      const int n = n0 + wn + 16*j + l15;
      const float bn = bias[n];
      #pragma unroll
      for (int i = 0; i < 4; ++i) {
        #pragma unroll
        for (int r = 0; r < 4; ++r) {
          const int m = m0 + wm + 16*i + quad * 4 + r;
          const float val = acc[i][j][r] + bn;
          if (MODE == 1) {
            const int sec = n >> 10, d = n & 1023;
            const int h = d >> 6, hd = d & 63;
            const int b = m >> 11, s = m & 2047;
            const int bh = b * NH + h;
            if (sec == 0) o0[((size_t)bh * SQ + s) * HDIM + hd] = f2bf(val);
            else          o1[((size_t)bh * SQ + s) * HDIM + hd] = f2bf(val);
          } else {
            of[(size_t)m * DIM + n] = val;
          }
        }
      }
    }
  }
}

// ---------------------------------------------------------------------------
// Causal flash attention, S^T formulation, exp2-domain softmax.
// grid = (BATCH*NH, SQ/128); block = 256 (4 waves x 32 Q rows).
// ---------------------------------------------------------------------------
#define LP 72  // 64 + 8 pad

__global__ __launch_bounds__(256)
void attn_fused(const u16* __restrict__ q_ws, const u16* __restrict__ k_ws,
                const u16* __restrict__ v_t, u16* __restrict__ y_ws)
{
  __shared__ __align__(16) u16 K0[64 * 32], K1[64 * 32];
  __shared__ __align__(16) u16 V0[64 * 32], V1[64 * 32];
  __shared__ __align__(16) u16 Pls[4][32 * LP];

  const int bh = blockIdx.x;
  const int qb = (gridDim.y - 1) - blockIdx.y;   // heavy-first
  const int b = bh >> 4, h = bh & 15;
  const int t = threadIdx.x;
  const int lane = t & 63, wave = t >> 6;
  const int l15 = lane & 15, quad = lane >> 4;

  const u16* Q  = q_ws + (size_t)bh * SQ * HDIM;
  const u16* Kp = k_ws + (size_t)bh * SQ * HDIM;
  const u16* Vp = v_t  + (size_t)bh * HDIM * SQ;

  const int qrow = qb * 128 + wave * 32;

  bf16x8 qf[2][2];
  #pragma unroll
  for (int qi = 0; qi < 2; ++qi)
    #pragma unroll
    for (int ks = 0; ks < 2; ++ks)
      qf[qi][ks] = *(const bf16x8*)&Q[(size_t)(qrow + 16*qi + l15) * HDIM + ks * 32 + quad * 8];

  f32x4 o[2][4] = {};
  float m_q[2] = {-1e30f, -1e30f};    // log2-domain running max
  float l_q[2] = {};

  const int sr = wave * 16 + (lane >> 2);
  const int sc = (lane & 3) * 8;
  u16* const ldst_k0 = &K0[wave * 512];
  u16* const ldst_k1 = &K1[wave * 512];
  u16* const ldst_v0 = &V0[wave * 512];
  u16* const ldst_v1 = &V1[wave * 512];

  const float SCL = 0.125f * 1.44269504f;   // (1/sqrt(64)) * log2(e)

  const int ntiles = 2 * qb + 2;
  for (int kvt = 0; kvt < ntiles; ++kvt) {
    const int kv0 = kvt * 64;
    gll16(&Kp[(size_t)(kv0 + sr) * HDIM + sc],      ldst_k0);
    gll16(&Kp[(size_t)(kv0 + sr) * HDIM + sc + 32], ldst_k1);
    gll16(&Vp[(size_t)sr * SQ + kv0 + sc],          ldst_v0);
    gll16(&Vp[(size_t)sr * SQ + kv0 + sc + 32],     ldst_v1);
    __syncthreads();

    if (kv0 <= qrow + 31) {
      // S^T = K * Q^T : st[kt][qi], rows kv=kv0+16kt+quad*4+r, cols q=qrow+16qi+l15
      f32x4 st[4][2] = {};
      #pragma unroll
      for (int ks = 0; ks < 2; ++ks) {
        const u16* Kls = ks ? K1 : K0;
        #pragma unroll
        for (int kt = 0; kt < 4; ++kt) {
          bf16x8 kf = *(const bf16x8*)&Kls[(16*kt + l15) * 32 + quad * 8];
          #pragma unroll
          for (int qi = 0; qi < 2; ++qi)
            st[kt][qi] = __builtin_amdgcn_mfma_f32_16x16x32_bf16(kf, qf[qi][ks], st[kt][qi], 0, 0, 0);
        }
      }

      const bool needs_mask = (kv0 + 63) > qrow;
      float alpha[2];
      #pragma unroll
      for (int qi = 0; qi < 2; ++qi) {
        const int q = qrow + 16*qi + l15;
        float tmax = -1e30f;
        #pragma unroll
        for (int kt = 0; kt < 4; ++kt)
          #pragma unroll
          for (int r = 0; r < 4; ++r) {
            float sv = st[kt][qi][r] * SCL;   // log2-domain logits
            if (needs_mask && (kv0 + 16*kt + quad*4 + r) > q) sv = -1e30f;
            st[kt][qi][r] = sv;
            tmax = fmaxf(tmax, sv);
          }
        tmax = fmaxf(tmax, __shfl_xor(tmax, 16));
        tmax = fmaxf(tmax, __shfl_xor(tmax, 32));
        const float mnew = fmaxf(m_q[qi], tmax);
        alpha[qi] = exp2f(m_q[qi] - mnew);
        float rsum = 0.f;
        #pragma unroll
        for (int kt = 0; kt < 4; ++kt)
          #pragma unroll
          for (int r = 0; r < 4; ++r) {
            const float pv = exp2f(st[kt][qi][r] - mnew);
            st[kt][qi][r] = pv;
            rsum += pv;
          }
        rsum += __shfl_xor(rsum, 16);
        rsum += __shfl_xor(rsum, 32);
        l_q[qi] = l_q[qi] * alpha[qi] + rsum;
        m_q[qi] = mnew;
      }

      // P^T (C-layout) -> P[q][kv] in LDS, packed 4 bf16 per b64 write
      #pragma unroll
      for (int qi = 0; qi < 2; ++qi)
        #pragma unroll
        for (int kt = 0; kt < 4; ++kt) {
          ushort4 pk;
          pk.x = f2bf(st[kt][qi][0]); pk.y = f2bf(st[kt][qi][1]);
          pk.z = f2bf(st[kt][qi][2]); pk.w = f2bf(st[kt][qi][3]);
          *(ushort4*)&Pls[wave][(16*qi + l15) * LP + 16*kt + quad * 4] = pk;
        }

      #pragma unroll
      for (int mi = 0; mi < 2; ++mi)
        #pragma unroll
        for (int r = 0; r < 4; ++r) {
          const float ar = __shfl(alpha[mi], quad * 4 + r);
          #pragma unroll
          for (int n = 0; n < 4; ++n) o[mi][n][r] *= ar;
        }

      #pragma unroll
      for (int ks = 0; ks < 2; ++ks) {
        const u16* Vls = ks ? V1 : V0;
        bf16x8 vf[4];
        #pragma unroll
        for (int n = 0; n < 4; ++n)
          vf[n] = *(const bf16x8*)&Vls[(16*n + l15) * 32 + quad * 8];
        #pragma unroll
        for (int mi = 0; mi < 2; ++mi) {
          bf16x8 pa = *(const bf16x8*)&Pls[wave][(16*mi + l15) * LP + ks * 32 + quad * 8];
          #pragma unroll
          for (int n = 0; n < 4; ++n)
            o[mi][n] = __builtin_amdgcn_mfma_f32_16x16x32_bf16(pa, vf[n], o[mi][n], 0, 0, 0);
        }
      }
    }
    __syncthreads();
  }

  #pragma unroll
  for (int mi = 0; mi < 2; ++mi)
    #pragma unroll
    for (int r = 0; r < 4; ++r) {
      const float lr = __shfl(l_q[mi], quad * 4 + r);
      const float inv = 1.0f / lr;
      const int qg = qrow + 16*mi + quad * 4 + r;
      #pragma unroll
      for (int n = 0; n < 4; ++n)
        y_ws[((size_t)b * SQ + qg) * DIM + h * HDIM + 16*n + l15] = f2bf(o[mi][n][r] * inv);
    }
}

// ---------------------------------------------------------------------------
extern "C" void kernel_launch(void* const* d_in, const int* in_sizes, int n_in,
                              void* d_out, int out_size, void* d_ws, size_t ws_size,
                              hipStream_t stream)
{
  const float* x      = (const float*)d_in[0];   // [4,2048,1024] fp32
  const float* W_attn = (const float*)d_in[1];   // [1024,3072]
  const float* b_attn = (const float*)d_in[2];   // [3072]
  const float* W_proj = (const float*)d_in[3];   // [1024,1024]
  const float* b_proj = (const float*)d_in[4];   // [1024]
  float* out = (float*)d_out;                    // [4,2048,1024] fp32

  char* ws = (char*)d_ws;
  u16* WattnT = (u16*)(ws);                  // [3072][1024] bf16, 6.29 MB
  u16* WprojT = (u16*)(ws + 6291456);        // [1024][1024] bf16, 2.10 MB
  u16* xb     = (u16*)(ws + 8388608);        // [8192][1024] bf16, 16.8 MB
  u16* y_ws   = xb;                          // aliases xb (dead after QKV GEMMs)
  u16* q_ws   = (u16*)(ws + 25165824);       // [64][2048][64] bf16
  u16* k_ws   = (u16*)(ws + 41943040);       // [64][2048][64] bf16
  u16* v_tw   = (u16*)(ws + 58720256);       // [64][64][2048] bf16 (V^T)
  // total: 75.5 MB

  const dim3 tb(32, 8);
  transpose_f32_bf16<<<dim3(3 * DIM / 32, DIM / 32), tb, 0, stream>>>(W_attn, WattnT, DIM, 3 * DIM);
  transpose_f32_bf16<<<dim3(DIM / 32, DIM / 32), tb, 0, stream>>>(W_proj, WprojT, DIM, DIM);
  f32_to_bf16_vec<<<(BATCH * SQ * DIM / 4 + 255) / 256, 256, 0, stream>>>(x, xb, BATCH * SQ * DIM / 4);

  // QK sections (N = 2048)
  gemm_bt<1><<<dim3(2 * DIM / 128, BATCH * SQ / 128), 256, 0, stream>>>(
      xb, WattnT, b_attn, DIM, q_ws, k_ws, nullptr);
  // V section (N = 1024), swapped-operand -> coalesced V^T stores
  gemm_bt<2><<<dim3(DIM / 128, BATCH * SQ / 128), 256, 0, stream>>>(
      xb, WattnT + (size_t)2048 * DIM, b_attn + 2048, DIM, v_tw, nullptr, nullptr);

  attn_fused<<<dim3(BATCH * NH, SQ / 128), 256, 0, stream>>>(q_ws, k_ws, v_tw, y_ws);

  gemm_bt<0><<<dim3(DIM / 128, BATCH * SQ / 128), 256, 0, stream>>>(
      y_ws, WprojT, b_proj, DIM, nullptr, nullptr, out);
}